// Round 6
// baseline (208.107 us; speedup 1.0000x reference)
//
#include <hip/hip_runtime.h>
#include <cstdint>

// CamPoseNet: bit-faithful JAX threefry replication (validated rounds 1-5).
// Round 6: occupancy + inline epilogue.
//  - GRID=1024 (C=1024 rows/block, 4 blocks/CU = 16 waves/CU): R5's 2
//    blocks/CU left VALUBusy at 53% (2 waves/SIMD can't hide dependency
//    stalls). Tail inflation worsens 1.33->1.6x but stall-hiding wins.
//  - E^T epilogue inlined at accept (R4-style, q prefetched at row-grab):
//    removes pass-2's __syncthreads (waves retire independently -> less
//    block-finish spread) and its extra out/q HBM round-trip.
//  - wave 0 produces the 96-entry split()-chain into LDS behind a watermark;
//    chain[t+1] prefetched at iteration top; next row+Z+q pre-grabbed at
//    accept (LDS-atomic queue, ~4.5 iterations of slack).
// All float ops on the accept-decision path use __f*_rn intrinsics (no FMA
// contraction) - matches XLA:CPU strict mul/add. Do not alter any arithmetic.

#define DEVI __device__ __forceinline__
#define MAXT 96
#define GRID 1024
#define NT 256

DEVI uint32_t rotl32(uint32_t v, int s) { return (v << s) | (v >> (32 - s)); }

// Threefry-2x32, 20 rounds (jax._src.prng.threefry2x32).
DEVI void tf2x32(uint32_t k0, uint32_t k1, uint32_t x0, uint32_t x1,
                 uint32_t& o0, uint32_t& o1) {
  const uint32_t kx = k0 ^ k1 ^ 0x1BD11BDAu;
  x0 += k0; x1 += k1;
#define TFR(r) x0 += x1; x1 = rotl32(x1, (r)); x1 ^= x0;
  TFR(13) TFR(15) TFR(26) TFR(6)
  x0 += k1; x1 += kx + 1u;
  TFR(17) TFR(29) TFR(16) TFR(24)
  x0 += kx; x1 += k0 + 2u;
  TFR(13) TFR(15) TFR(26) TFR(6)
  x0 += k0; x1 += k1 + 3u;
  TFR(17) TFR(29) TFR(16) TFR(24)
  x0 += k1; x1 += kx + 4u;
  TFR(13) TFR(15) TFR(26) TFR(6)
  x0 += kx; x1 += k0 + 5u;
#undef TFR
  o0 = x0; o1 = x1;
}

// XLA:CPU Cephes-style f32 log, strict mul/add. x > 0, normal.
DEVI float xla_logf_pos(float xf) {
  uint32_t bits = __float_as_uint(xf);
  float e = (float)((int)(bits >> 23) - 126);
  float m = __uint_as_float((bits & 0x007fffffu) | 0x3f000000u);  // [0.5,1)
  if (m < 0.70710678118654752440f) {
    e = __fsub_rn(e, 1.0f);
    m = __fadd_rn(__fsub_rn(m, 1.0f), m);
  } else {
    m = __fsub_rn(m, 1.0f);
  }
  float z = __fmul_rn(m, m);
  float y = 7.0376836292e-2f;
  y = __fadd_rn(__fmul_rn(y, m), -1.1514610310e-1f);
  y = __fadd_rn(__fmul_rn(y, m),  1.1676998740e-1f);
  y = __fadd_rn(__fmul_rn(y, m), -1.2420140846e-1f);
  y = __fadd_rn(__fmul_rn(y, m),  1.4249322787e-1f);
  y = __fadd_rn(__fmul_rn(y, m), -1.6668057665e-1f);
  y = __fadd_rn(__fmul_rn(y, m),  2.0000714765e-1f);
  y = __fadd_rn(__fmul_rn(y, m), -2.4999993993e-1f);
  y = __fadd_rn(__fmul_rn(y, m),  3.3333331174e-1f);
  y = __fmul_rn(y, m);
  y = __fmul_rn(y, z);
  y = __fadd_rn(y, __fmul_rn(e, -2.12194440e-4f));
  y = __fsub_rn(y, __fmul_rn(z, 0.5f));
  float r = __fadd_rn(m, y);
  r = __fadd_rn(r, __fmul_rn(e, 0.693359375f));
  return r;
}

// XLA EmitLog1p, select form (bit-identical per lane to the branchy version)
DEVI float xla_log1pf(float v) {
  float small = __fmul_rn(__fadd_rn(__fmul_rn(-0.5f, v), 1.0f), v);
  float big = xla_logf_pos(__fadd_rn(v, 1.0f));
  return (fabsf(v) < 1e-4f) ? small : big;
}

// XLA ErfInv32, coefficient-select form: identical op sequence per lane as
// the taken branch -> bit-exact, no dual-path exec-mask waste.
DEVI float xla_erfinvf(float x) {
  float w = -xla_log1pf(-__fmul_rn(x, x));
  bool c = (w < 5.0f);
  float qc = __fsub_rn(w, 2.5f);
  float qr = __fsub_rn(sqrtf(w), 3.0f);
  float q = c ? qc : qr;
  float p =                          c ? 2.81022636e-08f : -0.000200214257f;
  p = __fadd_rn(__fmul_rn(p, q), c ?  3.43273939e-07f :  0.000100950558f);
  p = __fadd_rn(__fmul_rn(p, q), c ? -3.5233877e-06f  :  0.00134934322f);
  p = __fadd_rn(__fmul_rn(p, q), c ? -4.39150654e-06f : -0.00367342844f);
  p = __fadd_rn(__fmul_rn(p, q), c ?  0.00021858087f  :  0.00573950773f);
  p = __fadd_rn(__fmul_rn(p, q), c ? -0.00125372503f  : -0.0076224613f);
  p = __fadd_rn(__fmul_rn(p, q), c ? -0.00417768164f  :  0.00943887047f);
  p = __fadd_rn(__fmul_rn(p, q), c ?  0.246640727f    :  1.00167406f);
  p = __fadd_rn(__fmul_rn(p, q), c ?  1.50140941f     :  2.83297682f);
  return __fmul_rn(p, x);
}

DEVI float u01_from_bits(uint32_t bits) {
  return __fsub_rn(__uint_as_float(0x3f800000u | (bits >> 9)), 1.0f);
}

// ---------------------------------------------------------------------------
__global__ __launch_bounds__(256) void campose_kernel(
    const float* __restrict__ q, const float* __restrict__ Z,
    float* __restrict__ out, const int* __restrict__ seedp, int N, int C) {
  __shared__ uint4 chain[MAXT + 1];
  __shared__ uint32_t next_row;
  __shared__ uint32_t wm;   // watermark: # of published chain entries

  const int tid = threadIdx.x;
  const int rbeg = blockIdx.x * C;
  const int rend = min(N, rbeg + C);
  if (tid == 0) { next_row = (uint32_t)(rbeg + 192); wm = 0u; }
  __syncthreads();

  const int wave = tid >> 6;
  if (wave == 0) {
    // Producer: lanes 0-2 of wave 0 walk the split() chain; publish each
    // entry with a release watermark. Other waves consume concurrently.
    int lane = tid & 63;
    uint32_t ka = 0u, kb = (uint32_t)seedp[0];
    uint32_t x1i = (lane == 2) ? 0u : (uint32_t)(lane + 1);
    for (int t = 0; t < MAXT; ++t) {
      uint32_t o0 = 0u, o1 = 0u;
      if (lane < 3) tf2x32(ka, kb, 0u, x1i, o0, o1);
      uint32_t s1a = __shfl(o0, 0, 64), s1b = __shfl(o1, 0, 64);
      uint32_t s2a = __shfl(o0, 1, 64), s2b = __shfl(o1, 1, 64);
      if (lane == 0) chain[t] = make_uint4(s1a, s1b, s2a, s2b);
      ka = __shfl(o0, 2, 64); kb = __shfl(o1, 2, 64);
      __threadfence_block();
      if (lane == 0) *(volatile uint32_t*)&wm = (uint32_t)(t + 1);
    }
    if (lane == 0) chain[MAXT] = make_uint4(0u, 0u, 0u, 0u);  // prefetch pad
    __threadfence_block();
    if (lane == 0) *(volatile uint32_t*)&wm = (uint32_t)(MAXT + 1);
  }

  const float sgi0 = __fadd_rn(1.0f, __fmul_rn(2.0f, 1e-6f));
  const float sig0 = sqrtf(__fdiv_rn(1.0f, sgi0));

  // --- per-lane row state: current row r + pre-grabbed next row rn ---
  int r, rn;
  if (wave == 0) {
    r  = (int)atomicAdd(&next_row, 1u);   // producer wave joins late; queue
    rn = (int)atomicAdd(&next_row, 1u);   // auto-balances
  } else {
    r  = rbeg + (tid - 64);               // static first 192 rows
    rn = (int)atomicAdd(&next_row, 1u);
  }
  bool have = (r < rend);
  float Zc0 = 0, Zc1 = 0, Zc2 = 0, Zn0 = 0, Zn1 = 0, Zn2 = 0;
  float4 qc = make_float4(0, 0, 0, 0), qn = make_float4(0, 0, 0, 0);
  if (have) {
    Zc0 = Z[r * 3 + 0]; Zc1 = Z[r * 3 + 1]; Zc2 = Z[r * 3 + 2];
    qc = *reinterpret_cast<const float4*>(q + (size_t)r * 4);
  }
  if (rn < rend) {
    Zn0 = Z[rn * 3 + 0]; Zn1 = Z[rn * 3 + 1]; Zn2 = Z[rn * 3 + 2];
    qn = *reinterpret_cast<const float4*>(q + (size_t)rn * 4);
  }

  // wait for chain[0]; cache it (reused at every accept)
  uint32_t wml = *(volatile uint32_t*)&wm;
  while (wml < 1u) wml = *(volatile uint32_t*)&wm;
  __threadfence_block();
  const uint4 ck0 = chain[0];
  uint4 ck = ck0;
  bool chain_all = (wml >= (uint32_t)(MAXT + 1));
  int t = 0;

  while (__ballot(have)) {
    if (have) {
      // prefetch next iteration's subkeys NOW (full iteration of slack)
      if (!chain_all) {
        uint32_t need = (uint32_t)(t + 2);
        uint32_t w_ = *(volatile uint32_t*)&wm;
        while (w_ < need) w_ = *(volatile uint32_t*)&wm;
        __threadfence_block();
        chain_all = (w_ >= (uint32_t)(MAXT + 1));
      }
      uint4 ckn = chain[t + 1];

      const uint32_t base = ((uint32_t)r) * 4u;

      // 4 normal variates (key = s1 subkey, counters base..base+3).
      float nv[4];
#pragma unroll
      for (int j = 0; j < 4; ++j) {
        uint32_t o0, o1;
        tf2x32(ck.x, ck.y, 0u, base + (uint32_t)j, o0, o1);
        float u = u01_from_bits(o0 ^ o1);
        float xin = __fadd_rn(__fmul_rn(u, 2.0f), -0.99999994f);
        xin = fmaxf(-0.99999994f, xin);
        nv[j] = __fmul_rn(1.41421356237309504880f, xla_erfinvf(xin));
      }

      // uniform draw (key = s2 subkey, counter r)
      uint32_t uo0, uo1;
      tf2x32(ck.z, ck.w, 0u, (uint32_t)r, uo0, uo1);
      float uu = u01_from_bits(uo0 ^ uo1);

      // row-dependent constants (Z prefetched a full row-lifetime ago)
      float lam1 = -Zc0, lam2 = -Zc1, lam3 = -Zc2;
      float sgi1 = __fadd_rn(1.0f, __fmul_rn(2.0f, lam1));
      float sgi2 = __fadd_rn(1.0f, __fmul_rn(2.0f, lam2));
      float sgi3 = __fadd_rn(1.0f, __fmul_rn(2.0f, lam3));
      float sig1 = sqrtf(__fdiv_rn(1.0f, sgi1));
      float sig2 = sqrtf(__fdiv_rn(1.0f, sgi2));
      float sig3 = sqrtf(__fdiv_rn(1.0f, sgi3));

      float y0 = __fmul_rn(nv[0], sig0);
      float y1 = __fmul_rn(nv[1], sig1);
      float y2v = __fmul_rn(nv[2], sig2);
      float y3 = __fmul_rn(nv[3], sig3);

      // normalize (sequential reduce order)
      float n2 = __fmul_rn(y0, y0);
      n2 = __fadd_rn(n2, __fmul_rn(y1, y1));
      n2 = __fadd_rn(n2, __fmul_rn(y2v, y2v));
      n2 = __fadd_rn(n2, __fmul_rn(y3, y3));
      float nr = sqrtf(n2);
      y0 = __fdiv_rn(y0, nr); y1 = __fdiv_rn(y1, nr);
      y2v = __fdiv_rn(y2v, nr); y3 = __fdiv_rn(y3, nr);

      float s0q = __fmul_rn(y0, y0), s1q = __fmul_rn(y1, y1);
      float s2q = __fmul_rn(y2v, y2v), s3q = __fmul_rn(y3, y3);

      float s1 = __fmul_rn(s0q, 1e-6f);
      s1 = __fadd_rn(s1, __fmul_rn(s1q, lam1));
      s1 = __fadd_rn(s1, __fmul_rn(s2q, lam2));
      s1 = __fadd_rn(s1, __fmul_rn(s3q, lam3));

      float s2 = __fmul_rn(s0q, sgi0);
      s2 = __fadd_rn(s2, __fmul_rn(s1q, sgi1));
      s2 = __fadd_rn(s2, __fmul_rn(s2q, sgi2));
      s2 = __fadd_rn(s2, __fmul_rn(s3q, sgi3));

      float lr = __fsub_rn(-s1, 2.7725887298583984f);  // 2*f32(ln 4)
      lr = __fadd_rn(lr, 1.5f);
      lr = __fadd_rn(lr, __fmul_rn(2.0f, xla_logf_pos(s2)));

      float lu = (uu > 0.0f) ? xla_logf_pos(uu) : -__builtin_inff();

      ++t;
      if ((lu < lr) || (t >= MAXT)) {
        // inline epilogue: qn = q/||q||, out = E^T y  (q prefetched at grab)
        float a = qc.x, b = qc.y, c = qc.z, d = qc.w;
        float qn2 = __fmul_rn(a, a);
        qn2 = __fadd_rn(qn2, __fmul_rn(b, b));
        qn2 = __fadd_rn(qn2, __fmul_rn(c, c));
        qn2 = __fadd_rn(qn2, __fmul_rn(d, d));
        float qnr = sqrtf(qn2);
        a = __fdiv_rn(a, qnr); b = __fdiv_rn(b, qnr);
        c = __fdiv_rn(c, qnr); d = __fdiv_rn(d, qnr);

        float o0v = __fadd_rn(__fadd_rn(__fadd_rn(__fmul_rn(a, y0), __fmul_rn(b, y1)),
                                        __fmul_rn(c, y2v)), __fmul_rn(d, y3));
        float o1v = __fadd_rn(__fadd_rn(__fadd_rn(__fmul_rn(-b, y0), __fmul_rn(a, y1)),
                                        __fmul_rn(-d, y2v)), __fmul_rn(c, y3));
        float o2v = __fadd_rn(__fadd_rn(__fadd_rn(__fmul_rn(-c, y0), __fmul_rn(d, y1)),
                                        __fmul_rn(a, y2v)), __fmul_rn(-b, y3));
        float o3v = __fadd_rn(__fadd_rn(__fadd_rn(__fmul_rn(d, y0), __fmul_rn(c, y1)),
                                        __fmul_rn(-b, y2v)), __fmul_rn(-a, y3));
        *reinterpret_cast<float4*>(out + (size_t)r * 4) =
            make_float4(o0v, o1v, o2v, o3v);

        // rotate in the pre-grabbed row; pre-grab the next one (slack ~4.5
        // iterations before first use)
        r = rn; Zc0 = Zn0; Zc1 = Zn1; Zc2 = Zn2; qc = qn;
        t = 0;
        ck = ck0;
        have = (r < rend);
        rn = (int)atomicAdd(&next_row, 1u);
        if (rn < rend) {
          Zn0 = Z[rn * 3 + 0]; Zn1 = Z[rn * 3 + 1]; Zn2 = Z[rn * 3 + 2];
          qn = *reinterpret_cast<const float4*>(q + (size_t)rn * 4);
        }
      } else {
        ck = ckn;
      }
    }
  }
}

extern "C" void kernel_launch(void* const* d_in, const int* in_sizes, int n_in,
                              void* d_out, int out_size, void* d_ws, size_t ws_size,
                              hipStream_t stream) {
  const float* q = (const float*)d_in[0];
  const float* Z = (const float*)d_in[1];
  const int* seed = (const int*)d_in[2];
  float* out = (float*)d_out;
  int N = in_sizes[0] / 4;

  int C = (N + GRID - 1) / GRID;  // rows per block (contiguous chunk)
  campose_kernel<<<GRID, NT, 0, stream>>>(q, Z, out, seed, N, C);
}